// Round 15
// baseline (664.248 us; speedup 1.0000x reference)
//
#include <hip/hip_runtime.h>
#include <hip/hip_bf16.h>

#define S3 64000          // 40*40*40
#define NB 2              // batch

// Packed weight offsets (floats) inside ws
constexpr int OFF_WUP   = 0;        // [tap][c][d]        8*32*64    = 16384
constexpr int OFF_WCONV = 16384;    // [tap][c64][co32]   27*64*32   = 55296
constexpr int OFF_W00   = 71680;    // [blk][tap][c32][co8]  3*27*32*8 = 20736
constexpr int OFF_W01   = 92416;    // [blk][tap][c8][co16]  3*27*8*16 = 10368
constexpr int OFF_W10   = 102784;   // [blk][c32][co8]       3*32*8    = 768
constexpr int OFF_W11   = 103552;   // [blk][tap][c8][co8]   3*27*8*8  = 5184
constexpr int OFF_W12   = 108736;   // [blk][c8][co16]       3*8*16    = 384
constexpr int OFF_ZERO  = 109120;   // 64 zeros (zero page for boundary taps)
constexpr int OFF_WCLS  = 109184;   // [tap][c32]            27*32     = 864
constexpr int NPACK     = 110048;

__device__ const int g_offtab[27] = {
  -1641, -1640, -1639, -1601, -1600, -1599, -1561, -1560, -1559,
    -41,   -40,   -39,    -1,     0,     1,    39,    40,    41,
   1559,  1560,  1561,  1599,  1600,  1601,  1639,  1640,  1641
};

// halo-space offsets for 10x10x6 tile halo, same tap order
__device__ const int g_hofftab[27] = {
  -67, -66, -65, -61, -60, -59, -55, -54, -53,
   -7,  -6,  -5,  -1,   0,   1,   5,   6,   7,
   53,  54,  55,  59,  60,  61,  65,  66,  67
};

__device__ __forceinline__ int occ_at(const int* __restrict__ x_occ, int b, int s) {
  int d2 = s % 40; int t = s / 40; int d1 = t % 40; int d0 = t / 40;
  return x_occ[b * 8000 + (d0 >> 1) * 400 + (d1 >> 1) * 20 + (d2 >> 1)] != 0;
}

__device__ __forceinline__ unsigned int f2key(float f) {
  unsigned int u = __float_as_uint(f);
  return (u & 0x80000000u) ? ~u : (u | 0x80000000u);
}

__device__ __forceinline__ unsigned int edge_mask27(int d0, int d1, int d2) {
  unsigned int m = 0;
  #pragma unroll
  for (int k0 = 0; k0 < 3; ++k0)
  #pragma unroll
  for (int k1 = 0; k1 < 3; ++k1)
  #pragma unroll
  for (int k2 = 0; k2 < 3; ++k2) {
    bool ok = (k0 == 0 ? (d0 > 0) : (k0 == 2 ? (d0 < 39) : true))
           && (k1 == 0 ? (d1 > 0) : (k1 == 2 ? (d1 < 39) : true))
           && (k2 == 0 ? (d2 > 0) : (k2 == 2 ? (d2 < 39) : true));
    if (ok) m |= 1u << ((k0 * 3 + k1) * 3 + k2);
  }
  return m;
}

// ---------------- weight packing ----------------
__global__ __launch_bounds__(256)
void pack_all(const float* __restrict__ Wup, const float* __restrict__ Wconv,
              const float* __restrict__ W00, const float* __restrict__ W01,
              const float* __restrict__ W10, const float* __restrict__ W11,
              const float* __restrict__ W12, const float* __restrict__ Wcls,
              float* __restrict__ wp) {
  int i = blockIdx.x * 256 + threadIdx.x;
  if (i < 16384) {  // W_up (32,64,2,2,2) -> [tap][c][d]
    int tap = i >> 11, rem = i & 2047, c = rem >> 6, d = rem & 63;
    wp[OFF_WUP + i] = Wup[((c << 6) | d) * 8 + tap];
    return;
  }
  i -= 16384;
  if (i < 55296) {  // W_conv (32,64,27) -> [tap][c][co]
    int tap = i >> 11, c = (i >> 5) & 63, co = i & 31;
    wp[OFF_WCONV + i] = Wconv[(co * 64 + c) * 27 + tap];
    return;
  }
  i -= 55296;
  if (i < 20736) {  // blk_W00 (3,8,32,27) -> [blk][tap][c][co]
    int blk = i / 6912, r = i - blk * 6912;
    int tap = r >> 8, c = (r >> 3) & 31, co = r & 7;
    wp[OFF_W00 + i] = W00[((blk * 8 + co) * 32 + c) * 27 + tap];
    return;
  }
  i -= 20736;
  if (i < 10368) {  // blk_W01 (3,16,8,27) -> [blk][tap][c][co]
    int blk = i / 3456, r = i - blk * 3456;
    int tap = r >> 7, c = (r >> 4) & 7, co = r & 15;
    wp[OFF_W01 + i] = W01[((blk * 16 + co) * 8 + c) * 27 + tap];
    return;
  }
  i -= 10368;
  if (i < 768) {    // blk_W10 (3,8,32) -> [blk][c][co]
    int blk = i / 256, r = i - blk * 256;
    int c = r >> 3, co = r & 7;
    wp[OFF_W10 + i] = W10[(blk * 8 + co) * 32 + c];
    return;
  }
  i -= 768;
  if (i < 5184) {   // blk_W11 (3,8,8,27) -> [blk][tap][c][co]
    int blk = i / 1728, r = i - blk * 1728;
    int tap = r >> 6, c = (r >> 3) & 7, co = r & 7;
    wp[OFF_W11 + i] = W11[((blk * 8 + co) * 8 + c) * 27 + tap];
    return;
  }
  i -= 5184;
  if (i < 384) {    // blk_W12 (3,16,8) -> [blk][c][co]
    int blk = i / 128, r = i - blk * 128;
    int c = r >> 4, co = r & 15;
    wp[OFF_W12 + i] = W12[(blk * 16 + co) * 8 + c];
    return;
  }
  i -= 384;
  if (i < 64) { wp[OFF_ZERO + i] = 0.f; return; }
  i -= 64;
  if (i < 864) {    // W_cls (1,32,27) -> [tap][c]
    int tap = i / 32, c = i % 32;
    wp[OFF_WCLS + i] = Wcls[c * 27 + tap];
  }
}

// ---------------- upsample (conv-transpose k=2 s=2) + relu + mask -> channels-last ----------------
__global__ __launch_bounds__(64)
void up_kernel(const float* __restrict__ xf, const float* __restrict__ wup,
               const float* __restrict__ bup, const int* __restrict__ x_occ,
               float* __restrict__ outA) {
  int pv = blockIdx.x * 64 + threadIdx.x;           // 0..15999
  int b = pv / 8000, p = pv - b * 8000;
  int p2 = p % 20, t = p / 20, p1 = t % 20, p0 = t / 20;
  int tap = blockIdx.y;
  int O0 = 2 * p0 + (tap >> 2), O1 = 2 * p1 + ((tap >> 1) & 1), O2 = 2 * p2 + (tap & 1);
  int s = O0 * 1600 + O1 * 40 + O2;
  float* op = outA + ((size_t)b * S3 + s) * 64;
  int occ = x_occ[pv];
  float4 z4 = make_float4(0.f, 0.f, 0.f, 0.f);
  if (!occ) {
    #pragma unroll
    for (int i = 0; i < 16; ++i) ((float4*)op)[i] = z4;
    return;
  }
  float acc[64];
  #pragma unroll
  for (int d = 0; d < 64; ++d) acc[d] = bup[d];
  const float* xb = xf + (size_t)b * 32 * 8000 + p;
  const float* wt = wup + tap * 2048;
  #pragma unroll 1
  for (int c = 0; c < 32; ++c) {
    float v = xb[c * 8000];
    const float* w = wt + c * 64;
    #pragma unroll
    for (int d = 0; d < 64; ++d) acc[d] = fmaf(v, w[d], acc[d]);
  }
  #pragma unroll
  for (int i = 0; i < 16; ++i)
    ((float4*)op)[i] = make_float4(fmaxf(acc[4*i],0.f), fmaxf(acc[4*i+1],0.f),
                                   fmaxf(acc[4*i+2],0.f), fmaxf(acc[4*i+3],0.f));
}

// ---------------- generic channels-last 3x3x3 conv (r6 shape: cout-split via blockIdx.y, tap unroll 2) ----------------
template<int CIN, int COUT, int WS, bool RELU>
__global__ __launch_bounds__(256)
void conv3_cl(const float* __restrict__ in, const float* __restrict__ w,
              const float* __restrict__ bias, const int* __restrict__ x_occ,
              const float* __restrict__ zpage, float* __restrict__ out, int outc) {
  int tid = blockIdx.x * 256 + threadIdx.x;
  int b = tid / S3, s = tid - b * S3;
  int d2 = s % 40; int t = s / 40; int d1 = t % 40; int d0 = t / 40;
  int occ = x_occ[b * 8000 + (d0 >> 1) * 400 + (d1 >> 1) * 20 + (d2 >> 1)];
  int cb = blockIdx.y * COUT;
  float* op = out + (size_t)tid * outc + cb;
  float4 z4 = make_float4(0.f, 0.f, 0.f, 0.f);
  if (!occ) {
    #pragma unroll
    for (int i = 0; i < COUT / 4; ++i) ((float4*)op)[i] = z4;
    return;
  }
  const float* wb = w + cb;
  const float* bb = bias + cb;
  float acc[COUT];
  #pragma unroll
  for (int c = 0; c < COUT; ++c) acc[c] = bb[c];
  const float* inb = in + (size_t)tid * CIN;
  unsigned int m27 = edge_mask27(d0, d1, d2);
  #pragma unroll 2
  for (int tap = 0; tap < 27; ++tap) {
    const float* p = ((m27 >> tap) & 1) ? (inb + g_offtab[tap] * CIN) : zpage;
    const float* wt = wb + tap * CIN * WS;
    #pragma unroll
    for (int c4 = 0; c4 < CIN / 4; ++c4) {
      float4 v = ((const float4*)p)[c4];
      const float* wc = wt + c4 * 4 * WS;
      #pragma unroll
      for (int c = 0; c < COUT; ++c) acc[c] = fmaf(v.x, wc[c], acc[c]);
      #pragma unroll
      for (int c = 0; c < COUT; ++c) acc[c] = fmaf(v.y, wc[WS + c], acc[c]);
      #pragma unroll
      for (int c = 0; c < COUT; ++c) acc[c] = fmaf(v.z, wc[2 * WS + c], acc[c]);
      #pragma unroll
      for (int c = 0; c < COUT; ++c) acc[c] = fmaf(v.w, wc[3 * WS + c], acc[c]);
    }
  }
  #pragma unroll
  for (int c = 0; c < COUT; ++c) if (RELU) acc[c] = fmaxf(acc[c], 0.f);
  #pragma unroll
  for (int c = 0; c < COUT / 4; ++c)
    ((float4*)op)[c] = make_float4(acc[4*c], acc[4*c+1], acc[4*c+2], acc[4*c+3]);
}

// ---------------- inception K1: T0 = relu(conv3(cur,W00)), T1 = relu(conv1(cur,W10)) ----------------
__global__ __launch_bounds__(256)
void conv_k1(const float* __restrict__ in, const float* __restrict__ w3,
             const float* __restrict__ w1, const float* __restrict__ b3,
             const float* __restrict__ b1, const int* __restrict__ x_occ,
             const float* __restrict__ zpage, float* __restrict__ T0o,
             float* __restrict__ T1o) {
  int tid = blockIdx.x * 256 + threadIdx.x;
  int b = tid / S3, s = tid - b * S3;
  int d2 = s % 40; int t = s / 40; int d1 = t % 40; int d0 = t / 40;
  int occ = x_occ[b * 8000 + (d0 >> 1) * 400 + (d1 >> 1) * 20 + (d2 >> 1)];
  float* o0 = T0o + (size_t)tid * 8;
  float* o1 = T1o + (size_t)tid * 8;
  float4 z4 = make_float4(0.f, 0.f, 0.f, 0.f);
  if (!occ) {
    ((float4*)o0)[0] = z4; ((float4*)o0)[1] = z4;
    ((float4*)o1)[0] = z4; ((float4*)o1)[1] = z4;
    return;
  }
  float a0[8], a1[8];
  #pragma unroll
  for (int co = 0; co < 8; ++co) { a0[co] = b3[co]; a1[co] = b1[co]; }
  const float* inb = in + (size_t)tid * 32;
  #pragma unroll
  for (int c4 = 0; c4 < 8; ++c4) {
    float4 v = ((const float4*)inb)[c4];
    const float* wc = w1 + c4 * 4 * 8;
    #pragma unroll
    for (int co = 0; co < 8; ++co) a1[co] = fmaf(v.x, wc[co], a1[co]);
    #pragma unroll
    for (int co = 0; co < 8; ++co) a1[co] = fmaf(v.y, wc[8 + co], a1[co]);
    #pragma unroll
    for (int co = 0; co < 8; ++co) a1[co] = fmaf(v.z, wc[16 + co], a1[co]);
    #pragma unroll
    for (int co = 0; co < 8; ++co) a1[co] = fmaf(v.w, wc[24 + co], a1[co]);
  }
  unsigned int m27 = edge_mask27(d0, d1, d2);
  #pragma unroll 2
  for (int tap = 0; tap < 27; ++tap) {
    const float* p = ((m27 >> tap) & 1) ? (inb + g_offtab[tap] * 32) : zpage;
    const float* wt = w3 + tap * 32 * 8;
    #pragma unroll
    for (int c4 = 0; c4 < 8; ++c4) {
      float4 v = ((const float4*)p)[c4];
      const float* wc = wt + c4 * 4 * 8;
      #pragma unroll
      for (int co = 0; co < 8; ++co) a0[co] = fmaf(v.x, wc[co], a0[co]);
      #pragma unroll
      for (int co = 0; co < 8; ++co) a0[co] = fmaf(v.y, wc[8 + co], a0[co]);
      #pragma unroll
      for (int co = 0; co < 8; ++co) a0[co] = fmaf(v.z, wc[16 + co], a0[co]);
      #pragma unroll
      for (int co = 0; co < 8; ++co) a0[co] = fmaf(v.w, wc[24 + co], a0[co]);
    }
  }
  ((float4*)o0)[0] = make_float4(fmaxf(a0[0],0.f), fmaxf(a0[1],0.f), fmaxf(a0[2],0.f), fmaxf(a0[3],0.f));
  ((float4*)o0)[1] = make_float4(fmaxf(a0[4],0.f), fmaxf(a0[5],0.f), fmaxf(a0[6],0.f), fmaxf(a0[7],0.f));
  ((float4*)o1)[0] = make_float4(fmaxf(a1[0],0.f), fmaxf(a1[1],0.f), fmaxf(a1[2],0.f), fmaxf(a1[3],0.f));
  ((float4*)o1)[1] = make_float4(fmaxf(a1[4],0.f), fmaxf(a1[5],0.f), fmaxf(a1[6],0.f), fmaxf(a1[7],0.f));
}

// ---------------- fused inception K3 with LDS-staged T0/T1 tiles ----------------
// grid: (500) blocks = NB * 250 spatial tiles of 8x8x4; 256 threads = 1 voxel each.
// halo 10x10x6 = 600 voxels staged per tensor (zeros outside volume == zpage semantics).
__global__ __launch_bounds__(256)
void conv_k3f(const float* __restrict__ t0, const float* __restrict__ t1,
              const float* __restrict__ resid, const float* __restrict__ w01,
              const float* __restrict__ w11, const float* __restrict__ w12,
              const float* __restrict__ bb01, const float* __restrict__ bb11,
              const float* __restrict__ bb12, const int* __restrict__ x_occ,
              float* __restrict__ nxt) {
  __shared__ float sh0[600 * 8];
  __shared__ float sh1[600 * 8];
  int bid = blockIdx.x;
  int b = bid / 250, tile = bid - b * 250;
  int tt0 = tile / 50, tt1 = (tile / 10) % 5, tt2 = tile % 10;
  int base0 = tt0 * 8, base1 = tt1 * 8, base2 = tt2 * 4;
  // stage halo (10x10x6) of T0 and T1
  for (int h = threadIdx.x; h < 600; h += 256) {
    int h0 = h / 60, r = h - h0 * 60, h1 = r / 6, h2 = r - h1 * 6;
    int g0 = base0 + h0 - 1, g1 = base1 + h1 - 1, g2 = base2 + h2 - 1;
    bool in = ((unsigned)g0 < 40u) && ((unsigned)g1 < 40u) && ((unsigned)g2 < 40u);
    float4 z4 = make_float4(0.f, 0.f, 0.f, 0.f);
    float4 v0a = z4, v0b = z4, v1a = z4, v1b = z4;
    if (in) {
      size_t gs = ((size_t)b * S3 + g0 * 1600 + g1 * 40 + g2) * 8;
      v0a = ((const float4*)(t0 + gs))[0];
      v0b = ((const float4*)(t0 + gs))[1];
      v1a = ((const float4*)(t1 + gs))[0];
      v1b = ((const float4*)(t1 + gs))[1];
    }
    ((float4*)(sh0 + h * 8))[0] = v0a;
    ((float4*)(sh0 + h * 8))[1] = v0b;
    ((float4*)(sh1 + h * 8))[0] = v1a;
    ((float4*)(sh1 + h * 8))[1] = v1b;
  }
  __syncthreads();
  // this thread's voxel
  int t0i = threadIdx.x >> 5, t1i = (threadIdx.x >> 2) & 7, t2i = threadIdx.x & 3;
  int d0 = base0 + t0i, d1 = base1 + t1i, d2 = base2 + t2i;
  int s = d0 * 1600 + d1 * 40 + d2;
  size_t tid = (size_t)b * S3 + s;
  int occ = x_occ[b * 8000 + (d0 >> 1) * 400 + (d1 >> 1) * 20 + (d2 >> 1)];
  float* op = nxt + tid * 32;
  float4 z4 = make_float4(0.f, 0.f, 0.f, 0.f);
  if (!occ) {
    #pragma unroll
    for (int i = 0; i < 8; ++i) ((float4*)op)[i] = z4;
    return;
  }
  float a[16], t2r[8];
  #pragma unroll
  for (int co = 0; co < 16; ++co) a[co] = bb01[co];
  #pragma unroll
  for (int co = 0; co < 8; ++co) t2r[co] = bb11[co];
  int hc = (t0i + 1) * 60 + (t1i + 1) * 6 + (t2i + 1);
  #pragma unroll 2
  for (int tap = 0; tap < 27; ++tap) {
    const float* p0 = sh0 + (hc + g_hofftab[tap]) * 8;
    const float* p1 = sh1 + (hc + g_hofftab[tap]) * 8;
    // branch0: W01 [tap][c8][co16]
    const float* wt0 = w01 + tap * 128;
    #pragma unroll
    for (int c4 = 0; c4 < 2; ++c4) {
      float4 v = ((const float4*)p0)[c4];
      const float* wc = wt0 + c4 * 64;
      #pragma unroll
      for (int co = 0; co < 16; ++co) a[co] = fmaf(v.x, wc[co], a[co]);
      #pragma unroll
      for (int co = 0; co < 16; ++co) a[co] = fmaf(v.y, wc[16 + co], a[co]);
      #pragma unroll
      for (int co = 0; co < 16; ++co) a[co] = fmaf(v.z, wc[32 + co], a[co]);
      #pragma unroll
      for (int co = 0; co < 16; ++co) a[co] = fmaf(v.w, wc[48 + co], a[co]);
    }
    // inner conv: W11 [tap][c8][co8]
    const float* wt1 = w11 + tap * 64;
    #pragma unroll
    for (int c4 = 0; c4 < 2; ++c4) {
      float4 v = ((const float4*)p1)[c4];
      const float* wc = wt1 + c4 * 32;
      #pragma unroll
      for (int co = 0; co < 8; ++co) t2r[co] = fmaf(v.x, wc[co], t2r[co]);
      #pragma unroll
      for (int co = 0; co < 8; ++co) t2r[co] = fmaf(v.y, wc[8 + co], t2r[co]);
      #pragma unroll
      for (int co = 0; co < 8; ++co) t2r[co] = fmaf(v.z, wc[16 + co], t2r[co]);
      #pragma unroll
      for (int co = 0; co < 8; ++co) t2r[co] = fmaf(v.w, wc[24 + co], t2r[co]);
    }
  }
  #pragma unroll
  for (int co = 0; co < 8; ++co) t2r[co] = fmaxf(t2r[co], 0.f);
  // branch1 1x1: W12 [c8][co16]
  float a1[16];
  #pragma unroll
  for (int co = 0; co < 16; ++co) a1[co] = bb12[co];
  #pragma unroll
  for (int c = 0; c < 8; ++c) {
    #pragma unroll
    for (int co = 0; co < 16; ++co) a1[co] = fmaf(t2r[c], w12[c * 16 + co], a1[co]);
  }
  const float* rb = resid + tid * 32;
  float o[32];
  #pragma unroll
  for (int co = 0; co < 16; ++co) { o[co] = a[co]; o[16 + co] = a1[co]; }
  #pragma unroll
  for (int q = 0; q < 8; ++q) {
    float4 r = ((const float4*)rb)[q];
    o[4*q] += r.x; o[4*q+1] += r.y; o[4*q+2] += r.z; o[4*q+3] += r.w;
  }
  #pragma unroll
  for (int q = 0; q < 8; ++q)
    ((float4*)op)[q] = make_float4(o[4*q], o[4*q+1], o[4*q+2], o[4*q+3]);
}

// ---------------- classifier conv (32 -> 1, 3x3x3) ----------------
__global__ __launch_bounds__(256)
void cls_kernel(const float* __restrict__ in, const float* __restrict__ w,
                const float* __restrict__ bias, const int* __restrict__ x_occ,
                const float* __restrict__ zpage, float* __restrict__ CLSo) {
  int tid = blockIdx.x * 256 + threadIdx.x;
  int b = tid / S3, s = tid - b * S3;
  int d2 = s % 40; int t = s / 40; int d1 = t % 40; int d0 = t / 40;
  int occ = x_occ[b * 8000 + (d0 >> 1) * 400 + (d1 >> 1) * 20 + (d2 >> 1)];
  if (!occ) { CLSo[tid] = 0.f; return; }
  float acc = bias[0];
  const float* inb = in + (size_t)tid * 32;
  unsigned int m27 = edge_mask27(d0, d1, d2);
  #pragma unroll 2
  for (int tap = 0; tap < 27; ++tap) {
    const float* p = ((m27 >> tap) & 1) ? (inb + g_offtab[tap] * 32) : zpage;
    const float* wt = w + tap * 32;
    #pragma unroll
    for (int c4 = 0; c4 < 8; ++c4) {
      float4 v = ((const float4*)p)[c4];
      acc = fmaf(v.x, wt[4*c4], acc);
      acc = fmaf(v.y, wt[4*c4+1], acc);
      acc = fmaf(v.z, wt[4*c4+2], acc);
      acc = fmaf(v.w, wt[4*c4+3], acc);
    }
  }
  CLSo[tid] = acc;
}

// ================= grid-parallel exact top-k (3x16-bit radix over 48-bit keys) =================
__global__ __launch_bounds__(256)
void sel_zero(int* __restrict__ hist) {
  int i = blockIdx.x * 256 + threadIdx.x;
  int n = 3 * NB * 65536 + NB * 16;
  for (int j = i; j < n; j += 512 * 256) hist[j] = 0;
}

__global__ __launch_bounds__(256)
void sel_hist1(const float* __restrict__ cls, const int* __restrict__ x_occ,
               const int* __restrict__ tgt, unsigned int* __restrict__ key,
               int* __restrict__ hist, int* __restrict__ sel) {
  int tid = blockIdx.x * 256 + threadIdx.x;
  int b = tid / S3, s = tid - b * S3;
  int occ = occ_at(x_occ, b, s);
  int tg = tgt[tid] != 0;
  unsigned int kk = occ ? f2key(cls[tid]) : 0u;
  key[tid] = kk;
  if (occ) atomicAdd(&hist[b * 65536 + (kk >> 16)], 1);
  unsigned long long bo = __ballot(occ);
  unsigned long long bt = __ballot(tg);
  if ((threadIdx.x & 63) == 0) {
    atomicAdd(&sel[b * 16 + 0], (int)__popcll(bo));
    atomicAdd(&sel[b * 16 + 1], (int)__popcll(bt));
  }
}

__global__ __launch_bounds__(256)
void sel_hist2(const unsigned int* __restrict__ key, const int* __restrict__ x_occ,
               int* __restrict__ hist, const int* __restrict__ sel) {
  int tid = blockIdx.x * 256 + threadIdx.x;
  int b = tid / S3, s = tid - b * S3;
  int B1 = sel[b * 16 + 4];
  if (B1 < 0) return;
  if (!occ_at(x_occ, b, s)) return;
  unsigned int kk = key[tid];
  if ((int)(kk >> 16) == B1) atomicAdd(&hist[(NB + b) * 65536 + (kk & 0xFFFFu)], 1);
}

__global__ __launch_bounds__(256)
void sel_hist3(const unsigned int* __restrict__ key, const int* __restrict__ x_occ,
               int* __restrict__ hist, const int* __restrict__ sel) {
  int tid = blockIdx.x * 256 + threadIdx.x;
  int b = tid / S3, s = tid - b * S3;
  int B1 = sel[b * 16 + 4];
  if (B1 < 0) return;
  if (!occ_at(x_occ, b, s)) return;
  unsigned int k32 = ((unsigned)B1 << 16) | (unsigned)sel[b * 16 + 5];
  if (key[tid] == k32) atomicAdd(&hist[(2 * NB + b) * 65536 + (65535 - s)], 1);
}

__global__ __launch_bounds__(256)
void sel_scan(int* __restrict__ hist, int* __restrict__ sel,
              const int* __restrict__ adaptive_flag, int phase) {
  int b = blockIdx.x;
  int* sb = sel + b * 16;
  __shared__ int chunk[256];
  __shared__ int s_active, s_rank;
  int t = threadIdx.x;
  if (t == 0) {
    int active = 1;
    if (phase == 0) {
      int k = min(sb[0], sb[1]);           // rho = 1.0
      sb[2] = k; sb[3] = k;
      if (!adaptive_flag[0] || k == 0) {
        sb[4] = -1000000;
        *(unsigned long long*)(sb + 6) = ~0ull;
        active = 0;
      }
    } else if (sb[4] == -1000000) {
      active = 0;
    }
    s_active = active; s_rank = sb[3];
  }
  __syncthreads();
  if (!s_active) return;
  const int* hb = hist + (phase * NB + b) * 65536;
  int sum = 0;
  #pragma unroll 4
  for (int v = 0; v < 256; ++v) sum += hb[t * 256 + v];
  chunk[t] = sum;
  __syncthreads();
  if (t == 0) {
    int r = s_rank, acc = 0, C = 0;
    for (int c = 255; c >= 0; --c) {
      if (acc + chunk[c] >= r) { C = c; r -= acc; break; }
      acc += chunk[c];
    }
    int B = C * 256;
    acc = 0;
    for (int v = 255; v >= 0; --v) {
      int h = hb[C * 256 + v];
      if (acc + h >= r) { B = C * 256 + v; r -= acc; break; }
      acc += h;
    }
    if (phase == 0)      { sb[4] = B; sb[3] = r; }
    else if (phase == 1) { sb[5] = B; sb[3] = r; }
    else {
      unsigned long long T = ((unsigned long long)sb[4] << 16) | (unsigned)sb[5];
      T = (T << 16) | (unsigned)B;
      *(unsigned long long*)(sb + 6) = T;
    }
  }
}

// ---------------- emit tail outputs + prune (channels-last -> channels-first) ----------------
__global__ __launch_bounds__(256)
void emit_prune(const float* __restrict__ cls, const unsigned int* __restrict__ key,
                const int* __restrict__ x_occ, const int* __restrict__ tgt,
                const int* __restrict__ adaptive_flag, const int* __restrict__ sel,
                const float* __restrict__ cur, float* __restrict__ dout) {
  int tid = blockIdx.x * 256 + threadIdx.x;
  int b = tid / S3, s = tid - b * S3;
  int occ = occ_at(x_occ, b, s);
  int tg = occ && (tgt[tid] != 0);
  float c = cls[tid];
  bool kp;
  if (adaptive_flag[0]) {
    unsigned long long T = *(const unsigned long long*)(sel + b * 16 + 6);
    unsigned long long k48 = ((unsigned long long)key[tid] << 16) | (unsigned)(65535 - s);
    kp = occ && (k48 >= T);
  } else {
    kp = occ && (c > 0.f);
  }
  kp = kp || tg;
  float* tail = dout + (size_t)NB * 32 * S3;
  tail[tid] = c;
  tail[NB * S3 + tid] = tg ? 1.f : 0.f;
  tail[2 * NB * S3 + tid] = kp ? 1.f : 0.f;
  float sc = kp ? 1.f : 0.f;
  const float4* ip = (const float4*)(cur + (size_t)tid * 32);
  float* ob = dout + (size_t)b * 32 * S3 + s;
  #pragma unroll
  for (int i = 0; i < 8; ++i) {
    float4 q = ip[i];
    ob[(4 * i) * S3] = q.x * sc; ob[(4 * i + 1) * S3] = q.y * sc;
    ob[(4 * i + 2) * S3] = q.z * sc; ob[(4 * i + 3) * S3] = q.w * sc;
  }
}

extern "C" void kernel_launch(void* const* d_in, const int* in_sizes, int n_in,
                              void* d_out, int out_size, void* d_ws, size_t ws_size,
                              hipStream_t stream) {
  const float* x_feat    = (const float*)d_in[0];
  const int*   x_occ     = (const int*)d_in[1];
  const int*   target_oc = (const int*)d_in[2];
  const float* W_up   = (const float*)d_in[3];
  const float* b_up   = (const float*)d_in[4];
  const float* W_conv = (const float*)d_in[5];
  const float* b_conv = (const float*)d_in[6];
  const float* W00 = (const float*)d_in[7];
  const float* b00 = (const float*)d_in[8];
  const float* W01 = (const float*)d_in[9];
  const float* b01 = (const float*)d_in[10];
  const float* W10 = (const float*)d_in[11];
  const float* b10 = (const float*)d_in[12];
  const float* W11 = (const float*)d_in[13];
  const float* b11 = (const float*)d_in[14];
  const float* W12 = (const float*)d_in[15];
  const float* b12 = (const float*)d_in[16];
  const float* W_cls = (const float*)d_in[17];
  const float* b_cls = (const float*)d_in[18];
  const int*   adaptive = (const int*)d_in[19];

  float* ws = (float*)d_ws;
  float* wp = ws;                          // packed weights + zero page
  float* zp = wp + OFF_ZERO;
  float* A  = ws + (1 << 17);              // [2*S3][64] channels-last up output
  float* B0 = A + (size_t)NB * S3 * 64;    // [2*S3][32]
  float* B1 = B0 + (size_t)NB * S3 * 32;   // [2*S3][32]
  // temporaries alias A (A fully consumed by the big conv before these are written)
  float* T0 = A;                           // [2*S3][8]
  float* T1 = T0 + (size_t)NB * S3 * 8;
  float* CLS = T1 + (size_t)NB * S3 * 8;   // [2*S3]
  unsigned int* KEY = (unsigned int*)(CLS + (size_t)NB * S3);
  int* HIST = (int*)(KEY + (size_t)NB * S3);   // [3][NB][65536]
  int* SEL  = HIST + 3 * NB * 65536;           // [NB][16]

  float* outf = (float*)d_out;

  pack_all<<<(NPACK + 255) / 256, 256, 0, stream>>>(W_up, W_conv, W00, W01, W10, W11, W12, W_cls, wp);
  up_kernel<<<dim3(250, 8), 64, 0, stream>>>(x_feat, wp + OFF_WUP, b_up, x_occ, A);
  conv3_cl<64, 16, 32, true><<<dim3(500, 2), 256, 0, stream>>>(A, wp + OFF_WCONV, b_conv, x_occ, zp, B0, 32);

  float* cur = B0;
  float* nxt = B1;
  for (int i = 0; i < 3; ++i) {
    conv_k1<<<500, 256, 0, stream>>>(cur, wp + OFF_W00 + i * 6912, wp + OFF_W10 + i * 256,
                                     b00 + i * 8, b10 + i * 8, x_occ, zp, T0, T1);
    conv_k3f<<<500, 256, 0, stream>>>(T0, T1, cur, wp + OFF_W01 + i * 3456, wp + OFF_W11 + i * 1728,
                                      wp + OFF_W12 + i * 128, b01 + i * 16, b11 + i * 8, b12 + i * 16,
                                      x_occ, nxt);
    float* tswap = cur; cur = nxt; nxt = tswap;
  }
  cls_kernel<<<500, 256, 0, stream>>>(cur, wp + OFF_WCLS, b_cls, x_occ, zp, CLS);

  // grid-parallel exact top-k
  sel_zero<<<512, 256, 0, stream>>>(HIST);
  sel_hist1<<<500, 256, 0, stream>>>(CLS, x_occ, target_oc, KEY, HIST, SEL);
  sel_scan<<<NB, 256, 0, stream>>>(HIST, SEL, adaptive, 0);
  sel_hist2<<<500, 256, 0, stream>>>(KEY, x_occ, HIST, SEL);
  sel_scan<<<NB, 256, 0, stream>>>(HIST, SEL, adaptive, 1);
  sel_hist3<<<500, 256, 0, stream>>>(KEY, x_occ, HIST, SEL);
  sel_scan<<<NB, 256, 0, stream>>>(HIST, SEL, adaptive, 2);
  emit_prune<<<500, 256, 0, stream>>>(CLS, KEY, x_occ, target_oc, adaptive, SEL, cur, outf);
}

// Round 17
// 631.460 us; speedup vs baseline: 1.0519x; 1.0519x over previous
//
#include <hip/hip_runtime.h>
#include <hip/hip_bf16.h>

#define S3 64000          // 40*40*40
#define NB 2              // batch

// Packed weight offsets (floats) inside ws
constexpr int OFF_WUP   = 0;        // [tap][c][d]        8*32*64    = 16384
constexpr int OFF_WCONV = 16384;    // [tap][c64][co32]   27*64*32   = 55296
constexpr int OFF_W00   = 71680;    // [blk][tap][c32][co8]  3*27*32*8 = 20736
constexpr int OFF_W01   = 92416;    // [blk][tap][c8][co16]  3*27*8*16 = 10368
constexpr int OFF_W10   = 102784;   // [blk][c32][co8]       3*32*8    = 768
constexpr int OFF_W11   = 103552;   // [blk][tap][c8][co8]   3*27*8*8  = 5184
constexpr int OFF_W12   = 108736;   // [blk][c8][co16]       3*8*16    = 384
constexpr int OFF_ZERO  = 109120;   // 64 zeros (zero page for boundary taps)
constexpr int OFF_WCLS  = 109184;   // [tap][c32]            27*32     = 864
constexpr int NPACK     = 110048;

__device__ const int g_offtab[27] = {
  -1641, -1640, -1639, -1601, -1600, -1599, -1561, -1560, -1559,
    -41,   -40,   -39,    -1,     0,     1,    39,    40,    41,
   1559,  1560,  1561,  1599,  1600,  1601,  1639,  1640,  1641
};

__device__ __forceinline__ int occ_at(const int* __restrict__ x_occ, int b, int s) {
  int d2 = s % 40; int t = s / 40; int d1 = t % 40; int d0 = t / 40;
  return x_occ[b * 8000 + (d0 >> 1) * 400 + (d1 >> 1) * 20 + (d2 >> 1)] != 0;
}

__device__ __forceinline__ unsigned int f2key(float f) {
  unsigned int u = __float_as_uint(f);
  return (u & 0x80000000u) ? ~u : (u | 0x80000000u);
}

__device__ __forceinline__ unsigned int edge_mask27(int d0, int d1, int d2) {
  unsigned int m = 0;
  #pragma unroll
  for (int k0 = 0; k0 < 3; ++k0)
  #pragma unroll
  for (int k1 = 0; k1 < 3; ++k1)
  #pragma unroll
  for (int k2 = 0; k2 < 3; ++k2) {
    bool ok = (k0 == 0 ? (d0 > 0) : (k0 == 2 ? (d0 < 39) : true))
           && (k1 == 0 ? (d1 > 0) : (k1 == 2 ? (d1 < 39) : true))
           && (k2 == 0 ? (d2 > 0) : (k2 == 2 ? (d2 < 39) : true));
    if (ok) m |= 1u << ((k0 * 3 + k1) * 3 + k2);
  }
  return m;
}

// ---------------- weight packing ----------------
__global__ __launch_bounds__(256)
void pack_all(const float* __restrict__ Wup, const float* __restrict__ Wconv,
              const float* __restrict__ W00, const float* __restrict__ W01,
              const float* __restrict__ W10, const float* __restrict__ W11,
              const float* __restrict__ W12, const float* __restrict__ Wcls,
              float* __restrict__ wp) {
  int i = blockIdx.x * 256 + threadIdx.x;
  if (i < 16384) {  // W_up (32,64,2,2,2) -> [tap][c][d]
    int tap = i >> 11, rem = i & 2047, c = rem >> 6, d = rem & 63;
    wp[OFF_WUP + i] = Wup[((c << 6) | d) * 8 + tap];
    return;
  }
  i -= 16384;
  if (i < 55296) {  // W_conv (32,64,27) -> [tap][c][co]
    int tap = i >> 11, c = (i >> 5) & 63, co = i & 31;
    wp[OFF_WCONV + i] = Wconv[(co * 64 + c) * 27 + tap];
    return;
  }
  i -= 55296;
  if (i < 20736) {  // blk_W00 (3,8,32,27) -> [blk][tap][c][co]
    int blk = i / 6912, r = i - blk * 6912;
    int tap = r >> 8, c = (r >> 3) & 31, co = r & 7;
    wp[OFF_W00 + i] = W00[((blk * 8 + co) * 32 + c) * 27 + tap];
    return;
  }
  i -= 20736;
  if (i < 10368) {  // blk_W01 (3,16,8,27) -> [blk][tap][c][co]
    int blk = i / 3456, r = i - blk * 3456;
    int tap = r >> 7, c = (r >> 4) & 7, co = r & 15;
    wp[OFF_W01 + i] = W01[((blk * 16 + co) * 8 + c) * 27 + tap];
    return;
  }
  i -= 10368;
  if (i < 768) {    // blk_W10 (3,8,32) -> [blk][c][co]
    int blk = i / 256, r = i - blk * 256;
    int c = r >> 3, co = r & 7;
    wp[OFF_W10 + i] = W10[(blk * 8 + co) * 32 + c];
    return;
  }
  i -= 768;
  if (i < 5184) {   // blk_W11 (3,8,8,27) -> [blk][tap][c][co]
    int blk = i / 1728, r = i - blk * 1728;
    int tap = r >> 6, c = (r >> 3) & 7, co = r & 7;
    wp[OFF_W11 + i] = W11[((blk * 8 + co) * 8 + c) * 27 + tap];
    return;
  }
  i -= 5184;
  if (i < 384) {    // blk_W12 (3,16,8) -> [blk][c][co]
    int blk = i / 128, r = i - blk * 128;
    int c = r >> 4, co = r & 15;
    wp[OFF_W12 + i] = W12[(blk * 16 + co) * 8 + c];
    return;
  }
  i -= 384;
  if (i < 64) { wp[OFF_ZERO + i] = 0.f; return; }
  i -= 64;
  if (i < 864) {    // W_cls (1,32,27) -> [tap][c]
    int tap = i / 32, c = i % 32;
    wp[OFF_WCLS + i] = Wcls[c * 27 + tap];
  }
}

// ---------------- upsample (conv-transpose k=2 s=2) + relu + mask -> channels-last ----------------
__global__ __launch_bounds__(64)
void up_kernel(const float* __restrict__ xf, const float* __restrict__ wup,
               const float* __restrict__ bup, const int* __restrict__ x_occ,
               float* __restrict__ outA) {
  int pv = blockIdx.x * 64 + threadIdx.x;           // 0..15999
  int b = pv / 8000, p = pv - b * 8000;
  int p2 = p % 20, t = p / 20, p1 = t % 20, p0 = t / 20;
  int tap = blockIdx.y;
  int O0 = 2 * p0 + (tap >> 2), O1 = 2 * p1 + ((tap >> 1) & 1), O2 = 2 * p2 + (tap & 1);
  int s = O0 * 1600 + O1 * 40 + O2;
  float* op = outA + ((size_t)b * S3 + s) * 64;
  int occ = x_occ[pv];
  float4 z4 = make_float4(0.f, 0.f, 0.f, 0.f);
  if (!occ) {
    #pragma unroll
    for (int i = 0; i < 16; ++i) ((float4*)op)[i] = z4;
    return;
  }
  float acc[64];
  #pragma unroll
  for (int d = 0; d < 64; ++d) acc[d] = bup[d];
  const float* xb = xf + (size_t)b * 32 * 8000 + p;
  const float* wt = wup + tap * 2048;
  #pragma unroll 1
  for (int c = 0; c < 32; ++c) {
    float v = xb[c * 8000];
    const float* w = wt + c * 64;
    #pragma unroll
    for (int d = 0; d < 64; ++d) acc[d] = fmaf(v, w[d], acc[d]);
  }
  #pragma unroll
  for (int i = 0; i < 16; ++i)
    ((float4*)op)[i] = make_float4(fmaxf(acc[4*i],0.f), fmaxf(acc[4*i+1],0.f),
                                   fmaxf(acc[4*i+2],0.f), fmaxf(acc[4*i+3],0.f));
}

// ---------------- generic channels-last 3x3x3 conv (r6 shape: cout-split via blockIdx.y, tap unroll 2) ----------------
template<int CIN, int COUT, int WS, bool RELU>
__global__ __launch_bounds__(256)
void conv3_cl(const float* __restrict__ in, const float* __restrict__ w,
              const float* __restrict__ bias, const int* __restrict__ x_occ,
              const float* __restrict__ zpage, float* __restrict__ out, int outc) {
  int tid = blockIdx.x * 256 + threadIdx.x;
  int b = tid / S3, s = tid - b * S3;
  int d2 = s % 40; int t = s / 40; int d1 = t % 40; int d0 = t / 40;
  int occ = x_occ[b * 8000 + (d0 >> 1) * 400 + (d1 >> 1) * 20 + (d2 >> 1)];
  int cb = blockIdx.y * COUT;
  float* op = out + (size_t)tid * outc + cb;
  float4 z4 = make_float4(0.f, 0.f, 0.f, 0.f);
  if (!occ) {
    #pragma unroll
    for (int i = 0; i < COUT / 4; ++i) ((float4*)op)[i] = z4;
    return;
  }
  const float* wb = w + cb;
  const float* bb = bias + cb;
  float acc[COUT];
  #pragma unroll
  for (int c = 0; c < COUT; ++c) acc[c] = bb[c];
  const float* inb = in + (size_t)tid * CIN;
  unsigned int m27 = edge_mask27(d0, d1, d2);
  #pragma unroll 2
  for (int tap = 0; tap < 27; ++tap) {
    const float* p = ((m27 >> tap) & 1) ? (inb + g_offtab[tap] * CIN) : zpage;
    const float* wt = wb + tap * CIN * WS;
    #pragma unroll
    for (int c4 = 0; c4 < CIN / 4; ++c4) {
      float4 v = ((const float4*)p)[c4];
      const float* wc = wt + c4 * 4 * WS;
      #pragma unroll
      for (int c = 0; c < COUT; ++c) acc[c] = fmaf(v.x, wc[c], acc[c]);
      #pragma unroll
      for (int c = 0; c < COUT; ++c) acc[c] = fmaf(v.y, wc[WS + c], acc[c]);
      #pragma unroll
      for (int c = 0; c < COUT; ++c) acc[c] = fmaf(v.z, wc[2 * WS + c], acc[c]);
      #pragma unroll
      for (int c = 0; c < COUT; ++c) acc[c] = fmaf(v.w, wc[3 * WS + c], acc[c]);
    }
  }
  #pragma unroll
  for (int c = 0; c < COUT; ++c) if (RELU) acc[c] = fmaxf(acc[c], 0.f);
  #pragma unroll
  for (int c = 0; c < COUT / 4; ++c)
    ((float4*)op)[c] = make_float4(acc[4*c], acc[4*c+1], acc[4*c+2], acc[4*c+3]);
}

// ---------------- inception K1: T0 = relu(conv3(cur,W00)), T1 = relu(conv1(cur,W10)) ----------------
__global__ __launch_bounds__(256)
void conv_k1(const float* __restrict__ in, const float* __restrict__ w3,
             const float* __restrict__ w1, const float* __restrict__ b3,
             const float* __restrict__ b1, const int* __restrict__ x_occ,
             const float* __restrict__ zpage, float* __restrict__ T0o,
             float* __restrict__ T1o) {
  int tid = blockIdx.x * 256 + threadIdx.x;
  int b = tid / S3, s = tid - b * S3;
  int d2 = s % 40; int t = s / 40; int d1 = t % 40; int d0 = t / 40;
  int occ = x_occ[b * 8000 + (d0 >> 1) * 400 + (d1 >> 1) * 20 + (d2 >> 1)];
  float* o0 = T0o + (size_t)tid * 8;
  float* o1 = T1o + (size_t)tid * 8;
  float4 z4 = make_float4(0.f, 0.f, 0.f, 0.f);
  if (!occ) {
    ((float4*)o0)[0] = z4; ((float4*)o0)[1] = z4;
    ((float4*)o1)[0] = z4; ((float4*)o1)[1] = z4;
    return;
  }
  float a0[8], a1[8];
  #pragma unroll
  for (int co = 0; co < 8; ++co) { a0[co] = b3[co]; a1[co] = b1[co]; }
  const float* inb = in + (size_t)tid * 32;
  #pragma unroll
  for (int c4 = 0; c4 < 8; ++c4) {
    float4 v = ((const float4*)inb)[c4];
    const float* wc = w1 + c4 * 4 * 8;
    #pragma unroll
    for (int co = 0; co < 8; ++co) a1[co] = fmaf(v.x, wc[co], a1[co]);
    #pragma unroll
    for (int co = 0; co < 8; ++co) a1[co] = fmaf(v.y, wc[8 + co], a1[co]);
    #pragma unroll
    for (int co = 0; co < 8; ++co) a1[co] = fmaf(v.z, wc[16 + co], a1[co]);
    #pragma unroll
    for (int co = 0; co < 8; ++co) a1[co] = fmaf(v.w, wc[24 + co], a1[co]);
  }
  unsigned int m27 = edge_mask27(d0, d1, d2);
  #pragma unroll 2
  for (int tap = 0; tap < 27; ++tap) {
    const float* p = ((m27 >> tap) & 1) ? (inb + g_offtab[tap] * 32) : zpage;
    const float* wt = w3 + tap * 32 * 8;
    #pragma unroll
    for (int c4 = 0; c4 < 8; ++c4) {
      float4 v = ((const float4*)p)[c4];
      const float* wc = wt + c4 * 4 * 8;
      #pragma unroll
      for (int co = 0; co < 8; ++co) a0[co] = fmaf(v.x, wc[co], a0[co]);
      #pragma unroll
      for (int co = 0; co < 8; ++co) a0[co] = fmaf(v.y, wc[8 + co], a0[co]);
      #pragma unroll
      for (int co = 0; co < 8; ++co) a0[co] = fmaf(v.z, wc[16 + co], a0[co]);
      #pragma unroll
      for (int co = 0; co < 8; ++co) a0[co] = fmaf(v.w, wc[24 + co], a0[co]);
    }
  }
  ((float4*)o0)[0] = make_float4(fmaxf(a0[0],0.f), fmaxf(a0[1],0.f), fmaxf(a0[2],0.f), fmaxf(a0[3],0.f));
  ((float4*)o0)[1] = make_float4(fmaxf(a0[4],0.f), fmaxf(a0[5],0.f), fmaxf(a0[6],0.f), fmaxf(a0[7],0.f));
  ((float4*)o1)[0] = make_float4(fmaxf(a1[0],0.f), fmaxf(a1[1],0.f), fmaxf(a1[2],0.f), fmaxf(a1[3],0.f));
  ((float4*)o1)[1] = make_float4(fmaxf(a1[4],0.f), fmaxf(a1[5],0.f), fmaxf(a1[6],0.f), fmaxf(a1[7],0.f));
}

// ---------------- fused inception K3 (r14 form): t2 = relu(conv3(T1,W11)) in registers;
// nxt[0:16]=conv3(T0,W01)+cur[0:16]; nxt[16:32]=conv1(t2,W12)+cur[16:32] ----------------
__global__ __launch_bounds__(256)
void conv_k3f(const float* __restrict__ t0, const float* __restrict__ t1,
              const float* __restrict__ resid, const float* __restrict__ w01,
              const float* __restrict__ w11, const float* __restrict__ w12,
              const float* __restrict__ bb01, const float* __restrict__ bb11,
              const float* __restrict__ bb12, const int* __restrict__ x_occ,
              const float* __restrict__ zpage, float* __restrict__ nxt) {
  int tid = blockIdx.x * 256 + threadIdx.x;
  int b = tid / S3, s = tid - b * S3;
  int d2 = s % 40; int t = s / 40; int d1 = t % 40; int d0 = t / 40;
  int occ = x_occ[b * 8000 + (d0 >> 1) * 400 + (d1 >> 1) * 20 + (d2 >> 1)];
  float* op = nxt + (size_t)tid * 32;
  float4 z4 = make_float4(0.f, 0.f, 0.f, 0.f);
  if (!occ) {
    #pragma unroll
    for (int i = 0; i < 8; ++i) ((float4*)op)[i] = z4;
    return;
  }
  float a[16], t2[8];
  #pragma unroll
  for (int co = 0; co < 16; ++co) a[co] = bb01[co];
  #pragma unroll
  for (int co = 0; co < 8; ++co) t2[co] = bb11[co];
  const float* t0b = t0 + (size_t)tid * 8;
  const float* t1b = t1 + (size_t)tid * 8;
  unsigned int m27 = edge_mask27(d0, d1, d2);
  #pragma unroll 2
  for (int tap = 0; tap < 27; ++tap) {
    bool ok = (m27 >> tap) & 1;
    const float* p0 = ok ? (t0b + g_offtab[tap] * 8) : zpage;
    const float* p1 = ok ? (t1b + g_offtab[tap] * 8) : zpage;
    const float* wt0 = w01 + tap * 128;
    #pragma unroll
    for (int c4 = 0; c4 < 2; ++c4) {
      float4 v = ((const float4*)p0)[c4];
      const float* wc = wt0 + c4 * 64;
      #pragma unroll
      for (int co = 0; co < 16; ++co) a[co] = fmaf(v.x, wc[co], a[co]);
      #pragma unroll
      for (int co = 0; co < 16; ++co) a[co] = fmaf(v.y, wc[16 + co], a[co]);
      #pragma unroll
      for (int co = 0; co < 16; ++co) a[co] = fmaf(v.z, wc[32 + co], a[co]);
      #pragma unroll
      for (int co = 0; co < 16; ++co) a[co] = fmaf(v.w, wc[48 + co], a[co]);
    }
    const float* wt1 = w11 + tap * 64;
    #pragma unroll
    for (int c4 = 0; c4 < 2; ++c4) {
      float4 v = ((const float4*)p1)[c4];
      const float* wc = wt1 + c4 * 32;
      #pragma unroll
      for (int co = 0; co < 8; ++co) t2[co] = fmaf(v.x, wc[co], t2[co]);
      #pragma unroll
      for (int co = 0; co < 8; ++co) t2[co] = fmaf(v.y, wc[8 + co], t2[co]);
      #pragma unroll
      for (int co = 0; co < 8; ++co) t2[co] = fmaf(v.z, wc[16 + co], t2[co]);
      #pragma unroll
      for (int co = 0; co < 8; ++co) t2[co] = fmaf(v.w, wc[24 + co], t2[co]);
    }
  }
  #pragma unroll
  for (int co = 0; co < 8; ++co) t2[co] = fmaxf(t2[co], 0.f);
  float a1[16];
  #pragma unroll
  for (int co = 0; co < 16; ++co) a1[co] = bb12[co];
  #pragma unroll
  for (int c = 0; c < 8; ++c) {
    #pragma unroll
    for (int co = 0; co < 16; ++co) a1[co] = fmaf(t2[c], w12[c * 16 + co], a1[co]);
  }
  const float* rb = resid + (size_t)tid * 32;
  float o[32];
  #pragma unroll
  for (int co = 0; co < 16; ++co) { o[co] = a[co]; o[16 + co] = a1[co]; }
  #pragma unroll
  for (int q = 0; q < 8; ++q) {
    float4 r = ((const float4*)rb)[q];
    o[4*q] += r.x; o[4*q+1] += r.y; o[4*q+2] += r.z; o[4*q+3] += r.w;
  }
  #pragma unroll
  for (int q = 0; q < 8; ++q)
    ((float4*)op)[q] = make_float4(o[4*q], o[4*q+1], o[4*q+2], o[4*q+3]);
}

// ---------------- classifier conv (32 -> 1) FUSED with sel_hist1 ----------------
__global__ __launch_bounds__(256)
void cls_hist(const float* __restrict__ in, const float* __restrict__ w,
              const float* __restrict__ bias, const int* __restrict__ x_occ,
              const float* __restrict__ zpage, const int* __restrict__ tgt,
              float* __restrict__ CLSo, unsigned int* __restrict__ key,
              int* __restrict__ hist, int* __restrict__ sel) {
  int tid = blockIdx.x * 256 + threadIdx.x;
  int b = tid / S3, s = tid - b * S3;
  int d2 = s % 40; int t = s / 40; int d1 = t % 40; int d0 = t / 40;
  int occ = x_occ[b * 8000 + (d0 >> 1) * 400 + (d1 >> 1) * 20 + (d2 >> 1)];
  float acc = 0.f;
  if (occ) {
    acc = bias[0];
    const float* inb = in + (size_t)tid * 32;
    unsigned int m27 = edge_mask27(d0, d1, d2);
    #pragma unroll 2
    for (int tap = 0; tap < 27; ++tap) {
      const float* p = ((m27 >> tap) & 1) ? (inb + g_offtab[tap] * 32) : zpage;
      const float* wt = w + tap * 32;
      #pragma unroll
      for (int c4 = 0; c4 < 8; ++c4) {
        float4 v = ((const float4*)p)[c4];
        acc = fmaf(v.x, wt[4*c4], acc);
        acc = fmaf(v.y, wt[4*c4+1], acc);
        acc = fmaf(v.z, wt[4*c4+2], acc);
        acc = fmaf(v.w, wt[4*c4+3], acc);
      }
    }
  }
  CLSo[tid] = acc;
  int tg = tgt[tid] != 0;
  unsigned int kk = occ ? f2key(acc) : 0u;
  key[tid] = kk;
  if (occ) atomicAdd(&hist[b * 65536 + (kk >> 16)], 1);
  unsigned long long bo = __ballot(occ);
  unsigned long long bt = __ballot(tg);
  if ((threadIdx.x & 63) == 0) {
    atomicAdd(&sel[b * 16 + 0], (int)__popcll(bo));
    atomicAdd(&sel[b * 16 + 1], (int)__popcll(bt));
  }
}

// ================= grid-parallel exact top-k (3x16-bit radix over 48-bit keys) =================
__global__ __launch_bounds__(256)
void sel_zero(int* __restrict__ hist) {
  int i = blockIdx.x * 256 + threadIdx.x;
  int n = 3 * NB * 65536 + NB * 16;
  for (int j = i; j < n; j += 512 * 256) hist[j] = 0;
}

__global__ __launch_bounds__(256)
void sel_hist2(const unsigned int* __restrict__ key, const int* __restrict__ x_occ,
               int* __restrict__ hist, const int* __restrict__ sel) {
  int tid = blockIdx.x * 256 + threadIdx.x;
  int b = tid / S3, s = tid - b * S3;
  int B1 = sel[b * 16 + 4];
  if (B1 < 0) return;
  if (!occ_at(x_occ, b, s)) return;
  unsigned int kk = key[tid];
  if ((int)(kk >> 16) == B1) atomicAdd(&hist[(NB + b) * 65536 + (kk & 0xFFFFu)], 1);
}

__global__ __launch_bounds__(256)
void sel_hist3(const unsigned int* __restrict__ key, const int* __restrict__ x_occ,
               int* __restrict__ hist, const int* __restrict__ sel) {
  int tid = blockIdx.x * 256 + threadIdx.x;
  int b = tid / S3, s = tid - b * S3;
  int B1 = sel[b * 16 + 4];
  if (B1 < 0) return;
  if (!occ_at(x_occ, b, s)) return;
  unsigned int k32 = ((unsigned)B1 << 16) | (unsigned)sel[b * 16 + 5];
  if (key[tid] == k32) atomicAdd(&hist[(2 * NB + b) * 65536 + (65535 - s)], 1);
}

__global__ __launch_bounds__(256)
void sel_scan(int* __restrict__ hist, int* __restrict__ sel,
              const int* __restrict__ adaptive_flag, int phase) {
  int b = blockIdx.x;
  int* sb = sel + b * 16;
  __shared__ int chunk[256];
  __shared__ int s_active, s_rank;
  int t = threadIdx.x;
  if (t == 0) {
    int active = 1;
    if (phase == 0) {
      int k = min(sb[0], sb[1]);           // rho = 1.0
      sb[2] = k; sb[3] = k;
      if (!adaptive_flag[0] || k == 0) {
        sb[4] = -1000000;
        *(unsigned long long*)(sb + 6) = ~0ull;
        active = 0;
      }
    } else if (sb[4] == -1000000) {
      active = 0;
    }
    s_active = active; s_rank = sb[3];
  }
  __syncthreads();
  if (!s_active) return;
  const int* hb = hist + (phase * NB + b) * 65536;
  int sum = 0;
  #pragma unroll 4
  for (int v = 0; v < 256; ++v) sum += hb[t * 256 + v];
  chunk[t] = sum;
  __syncthreads();
  if (t == 0) {
    int r = s_rank, acc = 0, C = 0;
    for (int c = 255; c >= 0; --c) {
      if (acc + chunk[c] >= r) { C = c; r -= acc; break; }
      acc += chunk[c];
    }
    int B = C * 256;
    acc = 0;
    for (int v = 255; v >= 0; --v) {
      int h = hb[C * 256 + v];
      if (acc + h >= r) { B = C * 256 + v; r -= acc; break; }
      acc += h;
    }
    if (phase == 0)      { sb[4] = B; sb[3] = r; }
    else if (phase == 1) { sb[5] = B; sb[3] = r; }
    else {
      unsigned long long T = ((unsigned long long)sb[4] << 16) | (unsigned)sb[5];
      T = (T << 16) | (unsigned)B;
      *(unsigned long long*)(sb + 6) = T;
    }
  }
}

// ---------------- emit tail outputs + prune (channels-last -> channels-first) ----------------
__global__ __launch_bounds__(256)
void emit_prune(const float* __restrict__ cls, const unsigned int* __restrict__ key,
                const int* __restrict__ x_occ, const int* __restrict__ tgt,
                const int* __restrict__ adaptive_flag, const int* __restrict__ sel,
                const float* __restrict__ cur, float* __restrict__ dout) {
  int tid = blockIdx.x * 256 + threadIdx.x;
  int b = tid / S3, s = tid - b * S3;
  int occ = occ_at(x_occ, b, s);
  int tg = occ && (tgt[tid] != 0);
  float c = cls[tid];
  bool kp;
  if (adaptive_flag[0]) {
    unsigned long long T = *(const unsigned long long*)(sel + b * 16 + 6);
    unsigned long long k48 = ((unsigned long long)key[tid] << 16) | (unsigned)(65535 - s);
    kp = occ && (k48 >= T);
  } else {
    kp = occ && (c > 0.f);
  }
  kp = kp || tg;
  float* tail = dout + (size_t)NB * 32 * S3;
  tail[tid] = c;
  tail[NB * S3 + tid] = tg ? 1.f : 0.f;
  tail[2 * NB * S3 + tid] = kp ? 1.f : 0.f;
  float sc = kp ? 1.f : 0.f;
  const float4* ip = (const float4*)(cur + (size_t)tid * 32);
  float* ob = dout + (size_t)b * 32 * S3 + s;
  #pragma unroll
  for (int i = 0; i < 8; ++i) {
    float4 q = ip[i];
    ob[(4 * i) * S3] = q.x * sc; ob[(4 * i + 1) * S3] = q.y * sc;
    ob[(4 * i + 2) * S3] = q.z * sc; ob[(4 * i + 3) * S3] = q.w * sc;
  }
}

extern "C" void kernel_launch(void* const* d_in, const int* in_sizes, int n_in,
                              void* d_out, int out_size, void* d_ws, size_t ws_size,
                              hipStream_t stream) {
  const float* x_feat    = (const float*)d_in[0];
  const int*   x_occ     = (const int*)d_in[1];
  const int*   target_oc = (const int*)d_in[2];
  const float* W_up   = (const float*)d_in[3];
  const float* b_up   = (const float*)d_in[4];
  const float* W_conv = (const float*)d_in[5];
  const float* b_conv = (const float*)d_in[6];
  const float* W00 = (const float*)d_in[7];
  const float* b00 = (const float*)d_in[8];
  const float* W01 = (const float*)d_in[9];
  const float* b01 = (const float*)d_in[10];
  const float* W10 = (const float*)d_in[11];
  const float* b10 = (const float*)d_in[12];
  const float* W11 = (const float*)d_in[13];
  const float* b11 = (const float*)d_in[14];
  const float* W12 = (const float*)d_in[15];
  const float* b12 = (const float*)d_in[16];
  const float* W_cls = (const float*)d_in[17];
  const float* b_cls = (const float*)d_in[18];
  const int*   adaptive = (const int*)d_in[19];

  float* ws = (float*)d_ws;
  float* wp = ws;                          // packed weights + zero page
  float* zp = wp + OFF_ZERO;
  float* A  = ws + (1 << 17);              // [2*S3][64] channels-last up output
  float* B0 = A + (size_t)NB * S3 * 64;    // [2*S3][32]
  float* B1 = B0 + (size_t)NB * S3 * 32;   // [2*S3][32]
  // temporaries alias A (A fully consumed by the big conv before these are written)
  float* T0 = A;                           // [2*S3][8]
  float* T1 = T0 + (size_t)NB * S3 * 8;
  float* CLS = T1 + (size_t)NB * S3 * 8;   // [2*S3]
  unsigned int* KEY = (unsigned int*)(CLS + (size_t)NB * S3);
  int* HIST = (int*)(KEY + (size_t)NB * S3);   // [3][NB][65536]
  int* SEL  = HIST + 3 * NB * 65536;           // [NB][16]

  float* outf = (float*)d_out;

  pack_all<<<(NPACK + 255) / 256, 256, 0, stream>>>(W_up, W_conv, W00, W01, W10, W11, W12, W_cls, wp);
  up_kernel<<<dim3(250, 8), 64, 0, stream>>>(x_feat, wp + OFF_WUP, b_up, x_occ, A);
  conv3_cl<64, 16, 32, true><<<dim3(500, 2), 256, 0, stream>>>(A, wp + OFF_WCONV, b_conv, x_occ, zp, B0, 32);

  float* cur = B0;
  float* nxt = B1;
  for (int i = 0; i < 3; ++i) {
    conv_k1<<<500, 256, 0, stream>>>(cur, wp + OFF_W00 + i * 6912, wp + OFF_W10 + i * 256,
                                     b00 + i * 8, b10 + i * 8, x_occ, zp, T0, T1);
    conv_k3f<<<500, 256, 0, stream>>>(T0, T1, cur, wp + OFF_W01 + i * 3456, wp + OFF_W11 + i * 1728,
                                      wp + OFF_W12 + i * 128, b01 + i * 16, b11 + i * 8, b12 + i * 16,
                                      x_occ, zp, nxt);
    float* tswap = cur; cur = nxt; nxt = tswap;
  }
  // HIST/SEL zeroing must precede the fused classifier+histogram kernel
  sel_zero<<<512, 256, 0, stream>>>(HIST);
  cls_hist<<<500, 256, 0, stream>>>(cur, wp + OFF_WCLS, b_cls, x_occ, zp, target_oc,
                                    CLS, KEY, HIST, SEL);
  sel_scan<<<NB, 256, 0, stream>>>(HIST, SEL, adaptive, 0);
  sel_hist2<<<500, 256, 0, stream>>>(KEY, x_occ, HIST, SEL);
  sel_scan<<<NB, 256, 0, stream>>>(HIST, SEL, adaptive, 1);
  sel_hist3<<<500, 256, 0, stream>>>(KEY, x_occ, HIST, SEL);
  sel_scan<<<NB, 256, 0, stream>>>(HIST, SEL, adaptive, 2);
  emit_prune<<<500, 256, 0, stream>>>(CLS, KEY, x_occ, target_oc, adaptive, SEL, cur, outf);
}